// Round 12
// baseline (131.375 us; speedup 1.0000x reference)
//
#include <hip/hip_runtime.h>
#include <math.h>

#define LSEQ 4096
#define MFFT 8192
#define NM   64
#define NBH  4096
#define TMAIN 512

__device__ __forceinline__ float2 cmulf(float2 a, float2 b) {
  return make_float2(a.x*b.x - a.y*b.y, a.x*b.y + a.y*b.x);
}
// a * conj(b) -- conj is free (operand negation folds into the FMAs)
__device__ __forceinline__ float2 cmulc(float2 a, float2 b) {
  return make_float2(a.x*b.x + a.y*b.y, a.y*b.x - a.x*b.y);
}
__device__ __forceinline__ float2 caddf(float2 a, float2 b){ return make_float2(a.x+b.x, a.y+b.y); }
__device__ __forceinline__ float2 csubf(float2 a, float2 b){ return make_float2(a.x-b.x, a.y-b.y); }
__device__ __forceinline__ float2 conjf(float2 a){ return make_float2(a.x, -a.y); }

// ---- radix-4 butterflies (validated r1..r11 lineage) ----
__device__ __forceinline__ void r4_fwd(float2& x0, float2& x1, float2& x2, float2& x3,
                                       float2 w1, float2 w2, float2 w3) {
  float2 A = caddf(x0,x2), C = csubf(x0,x2);
  float2 B = caddf(x1,x3), D = csubf(x1,x3);
  float2 y1 = make_float2(C.x + D.y, C.y - D.x);   // C - iD
  float2 y3 = make_float2(C.x - D.y, C.y + D.x);   // C + iD
  x0 = caddf(A,B);
  x1 = cmulf(y1,w1);
  x2 = cmulf(csubf(A,B),w2);
  x3 = cmulf(y3,w3);
}
// inverse butterfly taking FORWARD twiddles (conjugate applied inside, free)
__device__ __forceinline__ void r4_invc(float2& y0, float2& y1, float2& y2, float2& y3,
                                        float2 w1, float2 w2, float2 w3) {
  float2 c1 = cmulc(y1,w1);
  float2 c2 = cmulc(y2,w2);
  float2 c3 = cmulc(y3,w3);
  float2 ap = caddf(y0,c2), bp = csubf(y0,c2);
  float2 cp = caddf(c1,c3);
  float2 dp = make_float2(c3.y - c1.y, c1.x - c3.x);
  y0 = caddf(ap,cp); y1 = caddf(bp,dp); y2 = csubf(ap,cp); y3 = csubf(bp,dp);
}

// compile-time constants for the wA=1 (P3) stage
#define DECL_CONSTS \
  const float C16R[4]={1.f,0.9238795325112867f,0.7071067811865476f,0.3826834323650898f}; \
  const float C16I[4]={0.f,-0.3826834323650898f,-0.7071067811865476f,-0.9238795325112867f}; \
  const float C8R[4] ={1.f,0.7071067811865476f,0.f,-0.7071067811865476f}; \
  const float C8I[4] ={0.f,-0.7071067811865476f,-1.f,-0.7071067811865476f}; \
  const float C163R[4]={1.f,0.3826834323650898f,-0.7071067811865476f,-0.9238795325112867f}; \
  const float C163I[4]={0.f,-0.9238795325112867f,-0.7071067811865476f,0.3826834323650898f};

// const-twiddle fused radix-16 (P3): compiler folds all constant products
__device__ __forceinline__ void r16_fwd1(float2 x[16]) {
  DECL_CONSTS
  #pragma unroll
  for (int k0 = 0; k0 < 4; k0++)
    r4_fwd(x[k0], x[k0+4], x[k0+8], x[k0+12],
           make_float2(C16R[k0],C16I[k0]), make_float2(C8R[k0],C8I[k0]),
           make_float2(C163R[k0],C163I[k0]));
  #pragma unroll
  for (int q = 0; q < 4; q++)
    r4_fwd(x[4*q], x[4*q+1], x[4*q+2], x[4*q+3],
           make_float2(1.f,0.f), make_float2(1.f,0.f), make_float2(1.f,0.f));
}
__device__ __forceinline__ void r16_inv1(float2 x[16]) {
  DECL_CONSTS
  #pragma unroll
  for (int q = 0; q < 4; q++)
    r4_invc(x[4*q], x[4*q+1], x[4*q+2], x[4*q+3],
            make_float2(1.f,0.f), make_float2(1.f,0.f), make_float2(1.f,0.f));
  #pragma unroll
  for (int k0 = 0; k0 < 4; k0++)
    r4_invc(x[k0], x[k0+4], x[k0+8], x[k0+12],
            make_float2(C16R[k0],C16I[k0]), make_float2(C8R[k0],C8I[k0]),
            make_float2(C163R[k0],C163I[k0]));
}

// table-twiddle fused radix-16: tp[q] packs tw[2q],tw[2q+1];
// tw layout: [0..3]=w1[k0], [4..7]=w2[k0], [8..11]=w3[k0], [12]=wB, [13]=wB2, [14]=wB3
__device__ __forceinline__ void r16_fwd_t(float2 x[16], const float4 tp[8]) {
  float2 tw[16];
  #pragma unroll
  for (int q = 0; q < 8; q++) {
    tw[2*q]   = make_float2(tp[q].x, tp[q].y);
    tw[2*q+1] = make_float2(tp[q].z, tp[q].w);
  }
  #pragma unroll
  for (int k0 = 0; k0 < 4; k0++)
    r4_fwd(x[k0], x[k0+4], x[k0+8], x[k0+12], tw[k0], tw[4+k0], tw[8+k0]);
  #pragma unroll
  for (int q = 0; q < 4; q++)
    r4_fwd(x[4*q], x[4*q+1], x[4*q+2], x[4*q+3], tw[12], tw[13], tw[14]);
}
__device__ __forceinline__ void r16_inv_t(float2 x[16], const float4 tp[8]) {
  float2 tw[16];
  #pragma unroll
  for (int q = 0; q < 8; q++) {
    tw[2*q]   = make_float2(tp[q].x, tp[q].y);
    tw[2*q+1] = make_float2(tp[q].z, tp[q].w);
  }
  #pragma unroll
  for (int q = 0; q < 4; q++)
    r4_invc(x[4*q], x[4*q+1], x[4*q+2], x[4*q+3], tw[12], tw[13], tw[14]);
  #pragma unroll
  for (int k0 = 0; k0 < 4; k0++)
    r4_invc(x[k0], x[k0+4], x[k0+8], x[k0+12], tw[k0], tw[4+k0], tw[8+k0]);
}

// ---------------- prep: twiddle-pack tables, one entry per thread (wide grid) -------------
__device__ __forceinline__ float2 W8192e(long long e) {
  double ang = -2.0*M_PI*(double)(e & (MFFT-1))/(double)MFFT;
  return make_float2((float)cos(ang), (float)sin(ang));
}
__device__ __forceinline__ long long slotE(int s, long long a) {
  if (s < 4)  return a + 512LL*s;
  if (s < 8)  return 2LL*a + 1024LL*(s-4);
  if (s < 12) return 3LL*a + 1536LL*(s-8);
  if (s == 12) return 4LL*a;
  if (s == 13) return 8LL*a;
  if (s == 14) return 12LL*a;
  return 0;
}
__global__ void tables_kernel(float4* __restrict__ tp1, float4* __restrict__ tp2,
                              float2* __restrict__ ct2) {
  int idx = blockIdx.x*blockDim.x + threadIdx.x;
  if (idx < 4096) {                       // tp1[q*512+t]
    int q = idx >> 9, t = idx & 511;
    float2 wa = W8192e(slotE(2*q, t));
    float2 wb = (2*q+1 == 15) ? make_float2(1.f,0.f) : W8192e(slotE(2*q+1, t));
    tp1[q*512 + t] = make_float4(wa.x, wa.y, wb.x, wb.y);
  } else if (idx < 4352) {                // tp2[q*32+j], a = 16j
    int r = idx - 4096; int q = r >> 5, j = r & 31;
    long long a = 16LL*j;
    float2 wa = W8192e(slotE(2*q, a));
    float2 wb = (2*q+1 == 15) ? make_float2(1.f,0.f) : W8192e(slotE(2*q+1, a));
    tp2[q*32 + j] = make_float4(wa.x, wa.y, wb.x, wb.y);
  } else if (idx < 4368) {                // ct2[c] = W^{256c}
    int c = idx - 4352;
    ct2[c] = W8192e(256LL*c);
  }
}

// ---------------- prep: at_roots[k] via 4 Cauchy dots (double precision) ----------------
__global__ void cauchy_kernel(const float* __restrict__ Lre, const float* __restrict__ Lim,
                              const float* __restrict__ Pre, const float* __restrict__ Pim,
                              const float* __restrict__ Bre, const float* __restrict__ Bim,
                              const float* __restrict__ Cri, const float* __restrict__ lstep,
                              float2* __restrict__ a_out) {
  int k = blockIdx.x*blockDim.x + threadIdx.x;
  if (k >= LSEQ) return;
  double step = exp((double)lstep[0]);
  double ang = -2.0*M_PI*(double)k/(double)LSEQ;
  double wr = cos(ang), wi = sin(ang);
  double nr = 1.0 - wr, ni = -wi;
  double dr = 1.0 + wr, di = wi;
  double dn = dr*dr + di*di;
  double gre = (2.0/step) * (nr*dr + ni*di)/dn;
  double gim = (2.0/step) * (ni*dr - nr*di)/dn;
  double cre = 2.0*dr/dn, cim = -2.0*di/dn;
  double k00r=0,k00i=0,k01r=0,k01i=0,k10r=0,k10i=0,k11r=0,k11i=0;
  for (int n = 0; n < NM; n++) {
    double lre = Lre[n], lim = Lim[n];
    double pre = Pre[n], pim = Pim[n];
    double bre = Bre[n], bim = Bim[n];
    double ccr = Cri[2*n], cci = Cri[2*n+1];
    double er = gre - lre, ei = gim - lim;
    double inv = 1.0/(er*er + ei*ei);
    double ir =  er*inv, ii = -ei*inv;
    double v00r = ccr*bre + cci*bim, v00i = ccr*bim - cci*bre;
    double v01r = ccr*pre + cci*pim, v01i = ccr*pim - cci*pre;
    double v10r = pre*bre + pim*bim, v10i = pre*bim - pim*bre;
    double v11r = pre*pre + pim*pim, v11i = 0.0;
    k00r += v00r*ir - v00i*ii;  k00i += v00r*ii + v00i*ir;
    k01r += v01r*ir - v01i*ii;  k01i += v01r*ii + v01i*ir;
    k10r += v10r*ir - v10i*ii;  k10i += v10r*ii + v10i*ir;
    k11r += v11r*ir - v11i*ii;  k11i += v11r*ii + v11i*ir;
  }
  double numr = k01r*k10r - k01i*k10i, numi = k01r*k10i + k01i*k10r;
  double der = 1.0 + k11r, dei = k11i;
  double dinv = 1.0/(der*der + dei*dei);
  double qr = (numr*der + numi*dei)*dinv;
  double qi = (numi*der - numr*dei)*dinv;
  double tr = k00r - qr, ti = k00i - qi;
  double ar = cre*tr - cim*ti, ai = cre*ti + cim*tr;
  a_out[k] = make_float2((float)ar, (float)ai);
}

// ---------------- prep: K[l] = Re(IDFT_L(a))[l], 64 lanes per output ----------------
__global__ void ktime_kernel(const float2* __restrict__ a, float* __restrict__ K) {
  int lane = threadIdx.x & 63;
  int l = blockIdx.x * (blockDim.x >> 6) + (threadIdx.x >> 6);
  if (l >= LSEQ) return;
  double ang0 = 2.0*M_PI*(double)((l*lane) & (LSEQ-1))/(double)LSEQ;
  double tr = cos(ang0), ti = sin(ang0);
  double ang1 = 2.0*M_PI*(double)(l & 63)/64.0;
  double wr = cos(ang1), wi = sin(ang1);
  double acc = 0.0;
  for (int k = 0; k < 64; k++) {
    float2 ak = a[lane + (k << 6)];
    acc += (double)ak.x*tr - (double)ak.y*ti;
    double ntr = tr*wr - ti*wi;
    ti = tr*wi + ti*wr;
    tr = ntr;
  }
  for (int off = 32; off > 0; off >>= 1) acc += __shfl_down(acc, off);
  if (lane == 0) K[l] = (float)(acc/(double)LSEQ);
}

// ---------------- prep: Kd = fwd chain(pad(K + D*delta)) / M ----------------
__global__ void kd_kernel(const float* __restrict__ K, const float* __restrict__ Dp,
                          const float4* __restrict__ tp1, const float4* __restrict__ tp2,
                          const float2* __restrict__ ct2, float2* __restrict__ Kd) {
  __shared__ float2 z[MFFT];
  const int tid = threadIdx.x;
  float2 x[16];
  float4 tpr[8];
  #pragma unroll
  for (int q = 0; q < 8; q++) tpr[q] = tp1[(q<<9) + tid];
  // P1 (t=512); fold D*u into the kernel: K'[0] = K[0] + D
  #pragma unroll
  for (int k = 0; k < 8; k++) {
    float v = K[tid + 512*k];
    if (tid == 0 && k == 0) v += Dp[0];
    x[k] = make_float2(v, 0.f);
  }
  #pragma unroll
  for (int k = 8; k < 16; k++) x[k] = make_float2(0.f, 0.f);
  r16_fwd_t(x, tpr);
  {
    int xc = (tid >> 5) & 15; int p0 = tid ^ xc;
    #pragma unroll
    for (int k = 0; k < 16; k++) z[p0 + 512*k] = x[k];
  }
  __syncthreads();
  // P2 (t=32) + r2(s=16) via shfl
  const int j5 = tid & 31;
  const int Gb = (tid >> 5) << 9;
  float4 tq[8];
  #pragma unroll
  for (int q = 0; q < 8; q++) tq[q] = tp2[(q<<5) + j5];
  #pragma unroll
  for (int k = 0; k < 16; k++) x[k] = z[Gb + 32*k + (j5 ^ k)];
  r16_fwd_t(x, tq);
  {
    bool hi = (tid >> 4) & 1;
    float2 w32 = ct2[tid & 15];
    float2 weff = hi ? w32 : make_float2(1.f, 0.f);
    float s = hi ? -1.f : 1.f;
    #pragma unroll
    for (int k = 0; k < 16; k++) {
      float rx = __shfl_xor(x[k].x, 16);
      float ry = __shfl_xor(x[k].y, 16);
      float2 pre = make_float2(fmaf(x[k].x, s, rx), fmaf(x[k].y, s, ry));
      x[k] = cmulf(pre, weff);
    }
  }
  #pragma unroll
  for (int k = 0; k < 16; k++) z[Gb + 32*k + (j5 ^ k)] = x[k];
  __syncthreads();
  // P3: consecutive, const-twiddle r16, scale, store
  {
    int xc = (tid >> 1) & 15; int b16 = tid << 4;
    #pragma unroll
    for (int c = 0; c < 16; c++) x[c] = z[b16 + (c ^ xc)];
    r16_fwd1(x);
    const float sc = 1.0f/(float)MFFT;
    #pragma unroll
    for (int c = 0; c < 16; c++)
      Kd[b16 + c] = make_float2(x[c].x*sc, x[c].y*sc);
  }
}

// ---------------- main: 2 rows per block, 5 passes, 2 full barriers ----------------
// (512,2): VGPR cap 128, r11 measured 80 with no spill -> headroom used this round for
// CROSS-PHASE PREFETCH: wave_barrier/s_barrier are compiler scheduling fences, so hipcc
// cannot hoist the per-phase L2 table loads (Kd, tq, tpr) above them; each phase ate a
// ~200-400cy L2 bubble. Manual hoist: Kd loads issue after P1's barrier (hide under P2),
// tq loaded once and kept live P2->P4 (same values), P5's tpr issued at P4 start.
// Peak live ~112-120 regs (r4 datapoint: 112 clean at (512,2)). Spill tripwire: WRITE>65.5MB.
__global__ __launch_bounds__(TMAIN, 2)
void conv_kernel(const float* __restrict__ u,
                 const float4* __restrict__ tp1, const float4* __restrict__ tp2,
                 const float2* __restrict__ ct2, const float2* __restrict__ Kd,
                 float* __restrict__ out) {
  __shared__ float2 z[MFFT];
  const int tid = threadIdx.x;
  const int r0 = blockIdx.x, r1 = blockIdx.x + (NBH/2);
  const float* u0 = u + (size_t)r0*LSEQ;
  const float* u1 = u + (size_t)r1*LSEQ;
  float2 x[16];
  // ---- P1: global->regs, r16 fwd (t=512), regs->LDS ----
  {
    float4 tpr[8];
    #pragma unroll
    for (int q = 0; q < 8; q++) tpr[q] = tp1[(q<<9) + tid];
    #pragma unroll
    for (int k = 0; k < 8; k++)
      x[k] = make_float2(u0[tid + 512*k], u1[tid + 512*k]);
    #pragma unroll
    for (int k = 8; k < 16; k++) x[k] = make_float2(0.f, 0.f);
    r16_fwd_t(x, tpr);
    int xc = (tid >> 5) & 15; int p0 = tid ^ xc;
    #pragma unroll
    for (int k = 0; k < 16; k++) z[p0 + 512*k] = x[k];
  }
  __syncthreads();
  // ---- prefetch P3's Kd (L2-hot) -- latency hides under ALL of P2's compute ----
  const int b16 = tid << 4;
  float4 kd[8];
  {
    const float4* Kd4 = (const float4*)(Kd + b16);
    #pragma unroll
    for (int q = 0; q < 8; q++) kd[q] = Kd4[q];
  }
  // ---- P2: r16 fwd (t=32) + r2(s=16) tail via shfl_xor(16); tq stays live -> P4 ----
  const int j5 = tid & 31;
  const int Gb = (tid >> 5) << 9;
  const bool hi = (tid >> 4) & 1;
  const float2 w32 = ct2[tid & 15];
  const float sgn = hi ? -1.f : 1.f;
  float4 tq[8];
  #pragma unroll
  for (int q = 0; q < 8; q++) tq[q] = tp2[(q<<5) + j5];
  {
    #pragma unroll
    for (int k = 0; k < 16; k++) x[k] = z[Gb + 32*k + (j5 ^ k)];
    r16_fwd_t(x, tq);
    float2 weff = hi ? w32 : make_float2(1.f, 0.f);
    #pragma unroll
    for (int k = 0; k < 16; k++) {
      float rx = __shfl_xor(x[k].x, 16);
      float ry = __shfl_xor(x[k].y, 16);
      float2 pre = make_float2(fmaf(x[k].x, sgn, rx), fmaf(x[k].y, sgn, ry));
      x[k] = cmulf(pre, weff);
    }
    #pragma unroll
    for (int k = 0; k < 16; k++) z[Gb + 32*k + (j5 ^ k)] = x[k];
  }
  __builtin_amdgcn_wave_barrier();   // class-local: same-wave LDS ordering suffices
  // ---- P3: consecutive; const r16 fwd; x Kd (prefetched); const r16 inv ----
  {
    int xc = (tid >> 1) & 15;
    #pragma unroll
    for (int c = 0; c < 16; c++) x[c] = z[b16 + (c ^ xc)];
    r16_fwd1(x);
    #pragma unroll
    for (int c = 0; c < 8; c++) {
      x[2*c]   = cmulf(x[2*c],   make_float2(kd[c].x, kd[c].y));
      x[2*c+1] = cmulf(x[2*c+1], make_float2(kd[c].z, kd[c].w));
    }
    r16_inv1(x);
    #pragma unroll
    for (int c = 0; c < 16; c++) z[b16 + (c ^ xc)] = x[c];
  }
  __builtin_amdgcn_wave_barrier();   // class-local again
  // ---- P4: inv r2(s=16) head via shfl + r16 inv (t=32, reusing tq) ----
  // prefetch P5's twiddles here -- latency hides under P4 compute + final barrier
  float4 tpr5[8];
  #pragma unroll
  for (int q = 0; q < 8; q++) tpr5[q] = tp1[(q<<9) + tid];
  {
    #pragma unroll
    for (int k = 0; k < 16; k++) x[k] = z[Gb + 32*k + (j5 ^ k)];
    float2 weffc = hi ? conjf(w32) : make_float2(1.f, 0.f);
    #pragma unroll
    for (int k = 0; k < 16; k++) {
      float2 v = cmulf(x[k], weffc);
      float rx = __shfl_xor(v.x, 16);
      float ry = __shfl_xor(v.y, 16);
      x[k] = make_float2(fmaf(v.x, sgn, rx), fmaf(v.y, sgn, ry));
    }
    r16_inv_t(x, tq);
    #pragma unroll
    for (int k = 0; k < 16; k++) z[Gb + 32*k + (j5 ^ k)] = x[k];
  }
  __syncthreads();
  // ---- P5: r16 inv (t=512, prefetched twiddles), regs->global (D folded into Kd) ----
  {
    int xc = (tid >> 5) & 15; int p0 = tid ^ xc;
    #pragma unroll
    for (int k = 0; k < 16; k++) x[k] = z[p0 + 512*k];
    r16_inv_t(x, tpr5);
    float* o0 = out + (size_t)r0*LSEQ;
    float* o1 = out + (size_t)r1*LSEQ;
    #pragma unroll
    for (int k = 0; k < 8; k++) {
      int idx = tid + 512*k;
      o0[idx] = x[k].x;
      o1[idx] = x[k].y;
    }
  }
}

extern "C" void kernel_launch(void* const* d_in, const int* in_sizes, int n_in,
                              void* d_out, int out_size, void* d_ws, size_t ws_size,
                              hipStream_t stream) {
  const float* u     = (const float*)d_in[0];
  const float* Lre   = (const float*)d_in[1];
  const float* Lim   = (const float*)d_in[2];
  const float* Pre   = (const float*)d_in[3];
  const float* Pim   = (const float*)d_in[4];
  const float* Bre   = (const float*)d_in[5];
  const float* Bim   = (const float*)d_in[6];
  const float* Cri   = (const float*)d_in[7];
  const float* Dp    = (const float*)d_in[8];
  const float* lstep = (const float*)d_in[9];
  float* out = (float*)d_out;

  char* ws = (char*)d_ws;
  float2* a_ws  = (float2*)(ws);            //  32768 B : at_roots
  float*  K_ws  = (float*)(ws + 32768);     //  16384 B : K time domain
  float2* Kd_ws = (float2*)(ws + 49152);    //  65536 B : Kd (logical order, /M, +D folded)
  float4* tp1_ws= (float4*)(ws + 114688);   //  65536 B : P1/P5 twiddle packs [8][512]
  float4* tp2_ws= (float4*)(ws + 180224);   //   4096 B : P2/P4 twiddle packs [8][32]
  float2* ct2_ws= (float2*)(ws + 184320);   //    128 B : r2-stage twiddles

  hipLaunchKernelGGL(tables_kernel, dim3(18),   dim3(256), 0, stream,
                     tp1_ws, tp2_ws, ct2_ws);
  hipLaunchKernelGGL(cauchy_kernel, dim3(64),   dim3(64),  0, stream,
                     Lre, Lim, Pre, Pim, Bre, Bim, Cri, lstep, a_ws);
  hipLaunchKernelGGL(ktime_kernel,  dim3(1024), dim3(256), 0, stream, a_ws, K_ws);
  hipLaunchKernelGGL(kd_kernel,     dim3(1),    dim3(TMAIN), 0, stream,
                     K_ws, Dp, tp1_ws, tp2_ws, ct2_ws, Kd_ws);
  hipLaunchKernelGGL(conv_kernel,   dim3(NBH/2), dim3(TMAIN), 0, stream,
                     u, tp1_ws, tp2_ws, ct2_ws, Kd_ws, out);
}

// Round 13
// 118.941 us; speedup vs baseline: 1.1045x; 1.1045x over previous
//
#include <hip/hip_runtime.h>
#include <math.h>

#define LSEQ 4096
#define MFFT 8192
#define NM   64
#define NBH  4096
#define TMAIN 512

__device__ __forceinline__ float2 cmulf(float2 a, float2 b) {
  return make_float2(a.x*b.x - a.y*b.y, a.x*b.y + a.y*b.x);
}
// a * conj(b) -- conj is free (operand negation folds into the FMAs)
__device__ __forceinline__ float2 cmulc(float2 a, float2 b) {
  return make_float2(a.x*b.x + a.y*b.y, a.y*b.x - a.x*b.y);
}
__device__ __forceinline__ float2 caddf(float2 a, float2 b){ return make_float2(a.x+b.x, a.y+b.y); }
__device__ __forceinline__ float2 csubf(float2 a, float2 b){ return make_float2(a.x-b.x, a.y-b.y); }
__device__ __forceinline__ float2 conjf(float2 a){ return make_float2(a.x, -a.y); }

// ---- radix-4 butterflies (validated r1..r12 lineage) ----
__device__ __forceinline__ void r4_fwd(float2& x0, float2& x1, float2& x2, float2& x3,
                                       float2 w1, float2 w2, float2 w3) {
  float2 A = caddf(x0,x2), C = csubf(x0,x2);
  float2 B = caddf(x1,x3), D = csubf(x1,x3);
  float2 y1 = make_float2(C.x + D.y, C.y - D.x);   // C - iD
  float2 y3 = make_float2(C.x - D.y, C.y + D.x);   // C + iD
  x0 = caddf(A,B);
  x1 = cmulf(y1,w1);
  x2 = cmulf(csubf(A,B),w2);
  x3 = cmulf(y3,w3);
}
// inverse butterfly taking FORWARD twiddles (conjugate applied inside, free)
__device__ __forceinline__ void r4_invc(float2& y0, float2& y1, float2& y2, float2& y3,
                                        float2 w1, float2 w2, float2 w3) {
  float2 c1 = cmulc(y1,w1);
  float2 c2 = cmulc(y2,w2);
  float2 c3 = cmulc(y3,w3);
  float2 ap = caddf(y0,c2), bp = csubf(y0,c2);
  float2 cp = caddf(c1,c3);
  float2 dp = make_float2(c3.y - c1.y, c1.x - c3.x);
  y0 = caddf(ap,cp); y1 = caddf(bp,dp); y2 = csubf(ap,cp); y3 = csubf(bp,dp);
}

// compile-time constants for the wA=1 (P3) stage
#define DECL_CONSTS \
  const float C16R[4]={1.f,0.9238795325112867f,0.7071067811865476f,0.3826834323650898f}; \
  const float C16I[4]={0.f,-0.3826834323650898f,-0.7071067811865476f,-0.9238795325112867f}; \
  const float C8R[4] ={1.f,0.7071067811865476f,0.f,-0.7071067811865476f}; \
  const float C8I[4] ={0.f,-0.7071067811865476f,-1.f,-0.7071067811865476f}; \
  const float C163R[4]={1.f,0.3826834323650898f,-0.7071067811865476f,-0.9238795325112867f}; \
  const float C163I[4]={0.f,-0.9238795325112867f,-0.7071067811865476f,0.3826834323650898f};

// const-twiddle fused radix-16 (P3): compiler folds all constant products
__device__ __forceinline__ void r16_fwd1(float2 x[16]) {
  DECL_CONSTS
  #pragma unroll
  for (int k0 = 0; k0 < 4; k0++)
    r4_fwd(x[k0], x[k0+4], x[k0+8], x[k0+12],
           make_float2(C16R[k0],C16I[k0]), make_float2(C8R[k0],C8I[k0]),
           make_float2(C163R[k0],C163I[k0]));
  #pragma unroll
  for (int q = 0; q < 4; q++)
    r4_fwd(x[4*q], x[4*q+1], x[4*q+2], x[4*q+3],
           make_float2(1.f,0.f), make_float2(1.f,0.f), make_float2(1.f,0.f));
}
__device__ __forceinline__ void r16_inv1(float2 x[16]) {
  DECL_CONSTS
  #pragma unroll
  for (int q = 0; q < 4; q++)
    r4_invc(x[4*q], x[4*q+1], x[4*q+2], x[4*q+3],
            make_float2(1.f,0.f), make_float2(1.f,0.f), make_float2(1.f,0.f));
  #pragma unroll
  for (int k0 = 0; k0 < 4; k0++)
    r4_invc(x[k0], x[k0+4], x[k0+8], x[k0+12],
            make_float2(C16R[k0],C16I[k0]), make_float2(C8R[k0],C8I[k0]),
            make_float2(C163R[k0],C163I[k0]));
}

// table-twiddle fused radix-16: tp[q] packs tw[2q],tw[2q+1];
// tw layout: [0..3]=w1[k0], [4..7]=w2[k0], [8..11]=w3[k0], [12]=wB, [13]=wB2, [14]=wB3
__device__ __forceinline__ void r16_fwd_t(float2 x[16], const float4 tp[8]) {
  float2 tw[16];
  #pragma unroll
  for (int q = 0; q < 8; q++) {
    tw[2*q]   = make_float2(tp[q].x, tp[q].y);
    tw[2*q+1] = make_float2(tp[q].z, tp[q].w);
  }
  #pragma unroll
  for (int k0 = 0; k0 < 4; k0++)
    r4_fwd(x[k0], x[k0+4], x[k0+8], x[k0+12], tw[k0], tw[4+k0], tw[8+k0]);
  #pragma unroll
  for (int q = 0; q < 4; q++)
    r4_fwd(x[4*q], x[4*q+1], x[4*q+2], x[4*q+3], tw[12], tw[13], tw[14]);
}
__device__ __forceinline__ void r16_inv_t(float2 x[16], const float4 tp[8]) {
  float2 tw[16];
  #pragma unroll
  for (int q = 0; q < 8; q++) {
    tw[2*q]   = make_float2(tp[q].x, tp[q].y);
    tw[2*q+1] = make_float2(tp[q].z, tp[q].w);
  }
  #pragma unroll
  for (int q = 0; q < 4; q++)
    r4_invc(x[4*q], x[4*q+1], x[4*q+2], x[4*q+3], tw[12], tw[13], tw[14]);
  #pragma unroll
  for (int k0 = 0; k0 < 4; k0++)
    r4_invc(x[k0], x[k0+4], x[k0+8], x[k0+12], tw[k0], tw[4+k0], tw[8+k0]);
}

// ---------------- prep: twiddle-pack tables, one entry per thread (wide grid) -------------
__device__ __forceinline__ float2 W8192e(long long e) {
  double ang = -2.0*M_PI*(double)(e & (MFFT-1))/(double)MFFT;
  return make_float2((float)cos(ang), (float)sin(ang));
}
__device__ __forceinline__ long long slotE(int s, long long a) {
  if (s < 4)  return a + 512LL*s;
  if (s < 8)  return 2LL*a + 1024LL*(s-4);
  if (s < 12) return 3LL*a + 1536LL*(s-8);
  if (s == 12) return 4LL*a;
  if (s == 13) return 8LL*a;
  if (s == 14) return 12LL*a;
  return 0;
}
__global__ void tables_kernel(float4* __restrict__ tp1, float4* __restrict__ tp2,
                              float2* __restrict__ ct2) {
  int idx = blockIdx.x*blockDim.x + threadIdx.x;
  if (idx < 4096) {                       // tp1[q*512+t]
    int q = idx >> 9, t = idx & 511;
    float2 wa = W8192e(slotE(2*q, t));
    float2 wb = (2*q+1 == 15) ? make_float2(1.f,0.f) : W8192e(slotE(2*q+1, t));
    tp1[q*512 + t] = make_float4(wa.x, wa.y, wb.x, wb.y);
  } else if (idx < 4352) {                // tp2[q*32+j], a = 16j
    int r = idx - 4096; int q = r >> 5, j = r & 31;
    long long a = 16LL*j;
    float2 wa = W8192e(slotE(2*q, a));
    float2 wb = (2*q+1 == 15) ? make_float2(1.f,0.f) : W8192e(slotE(2*q+1, a));
    tp2[q*32 + j] = make_float4(wa.x, wa.y, wb.x, wb.y);
  } else if (idx < 4368) {                // ct2[c] = W^{256c}
    int c = idx - 4352;
    ct2[c] = W8192e(256LL*c);
  }
}

// ---------------- prep: at_roots[k] via 4 Cauchy dots (double precision) ----------------
__global__ void cauchy_kernel(const float* __restrict__ Lre, const float* __restrict__ Lim,
                              const float* __restrict__ Pre, const float* __restrict__ Pim,
                              const float* __restrict__ Bre, const float* __restrict__ Bim,
                              const float* __restrict__ Cri, const float* __restrict__ lstep,
                              float2* __restrict__ a_out) {
  int k = blockIdx.x*blockDim.x + threadIdx.x;
  if (k >= LSEQ) return;
  double step = exp((double)lstep[0]);
  double ang = -2.0*M_PI*(double)k/(double)LSEQ;
  double wr = cos(ang), wi = sin(ang);
  double nr = 1.0 - wr, ni = -wi;
  double dr = 1.0 + wr, di = wi;
  double dn = dr*dr + di*di;
  double gre = (2.0/step) * (nr*dr + ni*di)/dn;
  double gim = (2.0/step) * (ni*dr - nr*di)/dn;
  double cre = 2.0*dr/dn, cim = -2.0*di/dn;
  double k00r=0,k00i=0,k01r=0,k01i=0,k10r=0,k10i=0,k11r=0,k11i=0;
  for (int n = 0; n < NM; n++) {
    double lre = Lre[n], lim = Lim[n];
    double pre = Pre[n], pim = Pim[n];
    double bre = Bre[n], bim = Bim[n];
    double ccr = Cri[2*n], cci = Cri[2*n+1];
    double er = gre - lre, ei = gim - lim;
    double inv = 1.0/(er*er + ei*ei);
    double ir =  er*inv, ii = -ei*inv;
    double v00r = ccr*bre + cci*bim, v00i = ccr*bim - cci*bre;
    double v01r = ccr*pre + cci*pim, v01i = ccr*pim - cci*pre;
    double v10r = pre*bre + pim*bim, v10i = pre*bim - pim*bre;
    double v11r = pre*pre + pim*pim, v11i = 0.0;
    k00r += v00r*ir - v00i*ii;  k00i += v00r*ii + v00i*ir;
    k01r += v01r*ir - v01i*ii;  k01i += v01r*ii + v01i*ir;
    k10r += v10r*ir - v10i*ii;  k10i += v10r*ii + v10i*ir;
    k11r += v11r*ir - v11i*ii;  k11i += v11r*ii + v11i*ir;
  }
  double numr = k01r*k10r - k01i*k10i, numi = k01r*k10i + k01i*k10r;
  double der = 1.0 + k11r, dei = k11i;
  double dinv = 1.0/(der*der + dei*dei);
  double qr = (numr*der + numi*dei)*dinv;
  double qi = (numi*der - numr*dei)*dinv;
  double tr = k00r - qr, ti = k00i - qi;
  double ar = cre*tr - cim*ti, ai = cre*ti + cim*tr;
  a_out[k] = make_float2((float)ar, (float)ai);
}

// ---------------- prep: K[l] = Re(IDFT_L(a))[l], 64 lanes per output ----------------
__global__ void ktime_kernel(const float2* __restrict__ a, float* __restrict__ K) {
  int lane = threadIdx.x & 63;
  int l = blockIdx.x * (blockDim.x >> 6) + (threadIdx.x >> 6);
  if (l >= LSEQ) return;
  double ang0 = 2.0*M_PI*(double)((l*lane) & (LSEQ-1))/(double)LSEQ;
  double tr = cos(ang0), ti = sin(ang0);
  double ang1 = 2.0*M_PI*(double)(l & 63)/64.0;
  double wr = cos(ang1), wi = sin(ang1);
  double acc = 0.0;
  for (int k = 0; k < 64; k++) {
    float2 ak = a[lane + (k << 6)];
    acc += (double)ak.x*tr - (double)ak.y*ti;
    double ntr = tr*wr - ti*wi;
    ti = tr*wi + ti*wr;
    tr = ntr;
  }
  for (int off = 32; off > 0; off >>= 1) acc += __shfl_down(acc, off);
  if (lane == 0) K[l] = (float)(acc/(double)LSEQ);
}

// ---------------- prep: Kd = fwd chain(pad(K + D*delta)) / M ----------------
__global__ void kd_kernel(const float* __restrict__ K, const float* __restrict__ Dp,
                          const float4* __restrict__ tp1, const float4* __restrict__ tp2,
                          const float2* __restrict__ ct2, float2* __restrict__ Kd) {
  __shared__ float2 z[MFFT];
  const int tid = threadIdx.x;
  float2 x[16];
  float4 tpr[8];
  #pragma unroll
  for (int q = 0; q < 8; q++) tpr[q] = tp1[(q<<9) + tid];
  // P1 (t=512); fold D*u into the kernel: K'[0] = K[0] + D
  #pragma unroll
  for (int k = 0; k < 8; k++) {
    float v = K[tid + 512*k];
    if (tid == 0 && k == 0) v += Dp[0];
    x[k] = make_float2(v, 0.f);
  }
  #pragma unroll
  for (int k = 8; k < 16; k++) x[k] = make_float2(0.f, 0.f);
  r16_fwd_t(x, tpr);
  {
    int xc = (tid >> 5) & 15; int p0 = tid ^ xc;
    #pragma unroll
    for (int k = 0; k < 16; k++) z[p0 + 512*k] = x[k];
  }
  __syncthreads();
  // P2 (t=32) + r2(s=16) via shfl
  const int j5 = tid & 31;
  const int Gb = (tid >> 5) << 9;
  float4 tq[8];
  #pragma unroll
  for (int q = 0; q < 8; q++) tq[q] = tp2[(q<<5) + j5];
  #pragma unroll
  for (int k = 0; k < 16; k++) x[k] = z[Gb + 32*k + (j5 ^ k)];
  r16_fwd_t(x, tq);
  {
    bool hi = (tid >> 4) & 1;
    float2 w32 = ct2[tid & 15];
    float2 weff = hi ? w32 : make_float2(1.f, 0.f);
    float s = hi ? -1.f : 1.f;
    #pragma unroll
    for (int k = 0; k < 16; k++) {
      float rx = __shfl_xor(x[k].x, 16);
      float ry = __shfl_xor(x[k].y, 16);
      float2 pre = make_float2(fmaf(x[k].x, s, rx), fmaf(x[k].y, s, ry));
      x[k] = cmulf(pre, weff);
    }
  }
  #pragma unroll
  for (int k = 0; k < 16; k++) z[Gb + 32*k + (j5 ^ k)] = x[k];
  __syncthreads();
  // P3: consecutive, const-twiddle r16, scale, store
  {
    int xc = (tid >> 1) & 15; int b16 = tid << 4;
    #pragma unroll
    for (int c = 0; c < 16; c++) x[c] = z[b16 + (c ^ xc)];
    r16_fwd1(x);
    const float sc = 1.0f/(float)MFFT;
    #pragma unroll
    for (int c = 0; c < 16; c++)
      Kd[b16 + c] = make_float2(x[c].x*sc, x[c].y*sc);
  }
}

// ---------------- main: 2 rows per block, 5 passes, 2 full barriers ----------------
// (512,2): VGPR cap 128, measured allocation 80 -> zero spill, 2 blocks x 8 waves/CU.
// This is the r11-validated best (conv 114.5us, total 119.1us). r12's cross-phase
// prefetch (kd/tq/tpr held live across barriers) REGRESSED to 125us: +12 VGPR of
// live-range extension cost more in scheduling freedom than the L2 bubbles it hid.
// Occupancy ceiling analysis: 4 waves/SIMD is jointly forced by LDS (64KB z -> 2
// blocks/CU) and the VGPR quantization class (>64 regs -> max 4 waves/SIMD), so
// neither smaller LDS nor fewer regs can raise it for this algorithm class.
// P2->P3 and P3->P4 are class-local (class c = tid>>5 touches only z[512c..512c+512),
// threads [32c,32c+32) = same wave), so same-wave LDS ordering replaces __syncthreads.
__global__ __launch_bounds__(TMAIN, 2)
void conv_kernel(const float* __restrict__ u,
                 const float4* __restrict__ tp1, const float4* __restrict__ tp2,
                 const float2* __restrict__ ct2, const float2* __restrict__ Kd,
                 float* __restrict__ out) {
  __shared__ float2 z[MFFT];
  const int tid = threadIdx.x;
  const int r0 = blockIdx.x, r1 = blockIdx.x + (NBH/2);
  const float* u0 = u + (size_t)r0*LSEQ;
  const float* u1 = u + (size_t)r1*LSEQ;
  float2 x[16];
  // ---- P1: global->regs, r16 fwd (t=512), regs->LDS ----
  {
    float4 tpr[8];
    #pragma unroll
    for (int q = 0; q < 8; q++) tpr[q] = tp1[(q<<9) + tid];
    #pragma unroll
    for (int k = 0; k < 8; k++)
      x[k] = make_float2(u0[tid + 512*k], u1[tid + 512*k]);
    #pragma unroll
    for (int k = 8; k < 16; k++) x[k] = make_float2(0.f, 0.f);
    r16_fwd_t(x, tpr);
    int xc = (tid >> 5) & 15; int p0 = tid ^ xc;
    #pragma unroll
    for (int k = 0; k < 16; k++) z[p0 + 512*k] = x[k];
  }
  __syncthreads();
  // ---- P2: r16 fwd (t=32) + r2(s=16) tail via shfl_xor(16) ----
  const int j5 = tid & 31;
  const int Gb = (tid >> 5) << 9;
  const bool hi = (tid >> 4) & 1;
  const float2 w32 = ct2[tid & 15];
  const float sgn = hi ? -1.f : 1.f;
  {
    float4 tq[8];
    #pragma unroll
    for (int q = 0; q < 8; q++) tq[q] = tp2[(q<<5) + j5];
    #pragma unroll
    for (int k = 0; k < 16; k++) x[k] = z[Gb + 32*k + (j5 ^ k)];
    r16_fwd_t(x, tq);
    float2 weff = hi ? w32 : make_float2(1.f, 0.f);
    #pragma unroll
    for (int k = 0; k < 16; k++) {
      float rx = __shfl_xor(x[k].x, 16);
      float ry = __shfl_xor(x[k].y, 16);
      float2 pre = make_float2(fmaf(x[k].x, sgn, rx), fmaf(x[k].y, sgn, ry));
      x[k] = cmulf(pre, weff);
    }
    #pragma unroll
    for (int k = 0; k < 16; k++) z[Gb + 32*k + (j5 ^ k)] = x[k];
  }
  __builtin_amdgcn_wave_barrier();   // class-local: same-wave LDS ordering suffices
  // ---- P3: consecutive; const r16 fwd; x Kd; const r16 inv ----
  {
    int xc = (tid >> 1) & 15; int b16 = tid << 4;
    #pragma unroll
    for (int c = 0; c < 16; c++) x[c] = z[b16 + (c ^ xc)];
    float4 kd[8];
    const float4* Kd4 = (const float4*)(Kd + b16);
    #pragma unroll
    for (int q = 0; q < 8; q++) kd[q] = Kd4[q];
    r16_fwd1(x);
    #pragma unroll
    for (int c = 0; c < 8; c++) {
      x[2*c]   = cmulf(x[2*c],   make_float2(kd[c].x, kd[c].y));
      x[2*c+1] = cmulf(x[2*c+1], make_float2(kd[c].z, kd[c].w));
    }
    r16_inv1(x);
    #pragma unroll
    for (int c = 0; c < 16; c++) z[b16 + (c ^ xc)] = x[c];
  }
  __builtin_amdgcn_wave_barrier();   // class-local again
  // ---- P4: inv r2(s=16) head via shfl + r16 inv (t=32) ----
  {
    #pragma unroll
    for (int k = 0; k < 16; k++) x[k] = z[Gb + 32*k + (j5 ^ k)];
    float2 weffc = hi ? conjf(w32) : make_float2(1.f, 0.f);
    #pragma unroll
    for (int k = 0; k < 16; k++) {
      float2 v = cmulf(x[k], weffc);
      float rx = __shfl_xor(v.x, 16);
      float ry = __shfl_xor(v.y, 16);
      x[k] = make_float2(fmaf(v.x, sgn, rx), fmaf(v.y, sgn, ry));
    }
    float4 tq[8];
    #pragma unroll
    for (int q = 0; q < 8; q++) tq[q] = tp2[(q<<5) + j5];
    r16_inv_t(x, tq);
    #pragma unroll
    for (int k = 0; k < 16; k++) z[Gb + 32*k + (j5 ^ k)] = x[k];
  }
  __syncthreads();
  // ---- P5: r16 inv (t=512), regs->global (D already folded into Kd) ----
  {
    float4 tpr[8];
    #pragma unroll
    for (int q = 0; q < 8; q++) tpr[q] = tp1[(q<<9) + tid];
    int xc = (tid >> 5) & 15; int p0 = tid ^ xc;
    #pragma unroll
    for (int k = 0; k < 16; k++) x[k] = z[p0 + 512*k];
    r16_inv_t(x, tpr);
    float* o0 = out + (size_t)r0*LSEQ;
    float* o1 = out + (size_t)r1*LSEQ;
    #pragma unroll
    for (int k = 0; k < 8; k++) {
      int idx = tid + 512*k;
      o0[idx] = x[k].x;
      o1[idx] = x[k].y;
    }
  }
}

extern "C" void kernel_launch(void* const* d_in, const int* in_sizes, int n_in,
                              void* d_out, int out_size, void* d_ws, size_t ws_size,
                              hipStream_t stream) {
  const float* u     = (const float*)d_in[0];
  const float* Lre   = (const float*)d_in[1];
  const float* Lim   = (const float*)d_in[2];
  const float* Pre   = (const float*)d_in[3];
  const float* Pim   = (const float*)d_in[4];
  const float* Bre   = (const float*)d_in[5];
  const float* Bim   = (const float*)d_in[6];
  const float* Cri   = (const float*)d_in[7];
  const float* Dp    = (const float*)d_in[8];
  const float* lstep = (const float*)d_in[9];
  float* out = (float*)d_out;

  char* ws = (char*)d_ws;
  float2* a_ws  = (float2*)(ws);            //  32768 B : at_roots
  float*  K_ws  = (float*)(ws + 32768);     //  16384 B : K time domain
  float2* Kd_ws = (float2*)(ws + 49152);    //  65536 B : Kd (logical order, /M, +D folded)
  float4* tp1_ws= (float4*)(ws + 114688);   //  65536 B : P1/P5 twiddle packs [8][512]
  float4* tp2_ws= (float4*)(ws + 180224);   //   4096 B : P2/P4 twiddle packs [8][32]
  float2* ct2_ws= (float2*)(ws + 184320);   //    128 B : r2-stage twiddles

  hipLaunchKernelGGL(tables_kernel, dim3(18),   dim3(256), 0, stream,
                     tp1_ws, tp2_ws, ct2_ws);
  hipLaunchKernelGGL(cauchy_kernel, dim3(64),   dim3(64),  0, stream,
                     Lre, Lim, Pre, Pim, Bre, Bim, Cri, lstep, a_ws);
  hipLaunchKernelGGL(ktime_kernel,  dim3(1024), dim3(256), 0, stream, a_ws, K_ws);
  hipLaunchKernelGGL(kd_kernel,     dim3(1),    dim3(TMAIN), 0, stream,
                     K_ws, Dp, tp1_ws, tp2_ws, ct2_ws, Kd_ws);
  hipLaunchKernelGGL(conv_kernel,   dim3(NBH/2), dim3(TMAIN), 0, stream,
                     u, tp1_ws, tp2_ws, ct2_ws, Kd_ws, out);
}

// Round 15
// 118.273 us; speedup vs baseline: 1.1108x; 1.0056x over previous
//
#include <hip/hip_runtime.h>
#include <math.h>

#define LSEQ 4096
#define MFFT 8192
#define NM   64
#define NBH  4096

__device__ __forceinline__ float2 cmulf(float2 a, float2 b) {
  return make_float2(a.x*b.x - a.y*b.y, a.x*b.y + a.y*b.x);
}
// a * conj(b)
__device__ __forceinline__ float2 cmulc(float2 a, float2 b) {
  return make_float2(a.x*b.x + a.y*b.y, a.y*b.x - a.x*b.y);
}
__device__ __forceinline__ float2 caddf(float2 a, float2 b){ return make_float2(a.x+b.x, a.y+b.y); }
__device__ __forceinline__ float2 csubf(float2 a, float2 b){ return make_float2(a.x-b.x, a.y-b.y); }

// storage swizzle (r6-validated): low4 ^= bits4-7, bits4-7 ^= bits8-11. Bijective; keeps
// every 256-block in place. All pass patterns (strides 1024/128/16/2) at b64 bank floor.
__device__ __forceinline__ int ZS(int i){ return i ^ ((i>>4)&15) ^ (((i>>8)&15)<<4); }

// ---- 8-point DFT, DIF r2 cascade, outputs in natural freq order x[m]=F_m ----
__device__ __forceinline__ void dft8_fwd(float2 x[8]) {
  const float RC = 0.7071067811865476f;
  float2 u0=caddf(x[0],x[4]), v0=csubf(x[0],x[4]);
  float2 u1=caddf(x[1],x[5]), d1=csubf(x[1],x[5]);
  float2 u2=caddf(x[2],x[6]), d2=csubf(x[2],x[6]);
  float2 u3=caddf(x[3],x[7]), d3=csubf(x[3],x[7]);
  float2 v1 = make_float2(RC*(d1.x + d1.y), RC*(d1.y - d1.x));   // *W8^1=(c,-c)
  float2 v2 = make_float2(d2.y, -d2.x);                          // *(-i)
  float2 v3 = make_float2(RC*(d3.y - d3.x), -RC*(d3.x + d3.y));  // *W8^3=(-c,-c)
  float2 p0=caddf(u0,u2), q0=csubf(u0,u2);
  float2 p1=caddf(u1,u3), qt=csubf(u1,u3);
  float2 q1 = make_float2(qt.y, -qt.x);                          // *(-i)
  float2 r0=caddf(v0,v2), s0=csubf(v0,v2);
  float2 r1=caddf(v1,v3), st=csubf(v1,v3);
  float2 s1 = make_float2(st.y, -st.x);                          // *(-i)
  x[0]=caddf(p0,p1); x[4]=csubf(p0,p1);
  x[2]=caddf(q0,q1); x[6]=csubf(q0,q1);
  x[1]=caddf(r0,r1); x[5]=csubf(r0,r1);
  x[3]=caddf(s0,s1); x[7]=csubf(s0,s1);
}
// exact operation-reverse (unnormalized: inv(fwd) = 8*id; total 8192 folded into Kd)
__device__ __forceinline__ void dft8_inv(float2 x[8]) {
  const float RC = 0.7071067811865476f;
  float2 p0=caddf(x[0],x[4]), p1=csubf(x[0],x[4]);
  float2 q0=caddf(x[2],x[6]), q1=csubf(x[2],x[6]);
  float2 r0=caddf(x[1],x[5]), r1=csubf(x[1],x[5]);
  float2 s0=caddf(x[3],x[7]), s1=csubf(x[3],x[7]);
  float2 q1i = make_float2(-q1.y, q1.x);                         // *(+i)
  float2 s1i = make_float2(-s1.y, s1.x);
  float2 u0=caddf(p0,q0), u2=csubf(p0,q0);
  float2 u1=caddf(p1,q1i), u3=csubf(p1,q1i);
  float2 v0=caddf(r0,s0), v2=csubf(r0,s0);
  float2 v1=caddf(r1,s1i), v3=csubf(r1,s1i);
  float2 w1 = make_float2(RC*(v1.x - v1.y), RC*(v1.x + v1.y));   // *conj(W8^1)=(c,c)
  float2 w2 = make_float2(-v2.y, v2.x);                          // *(+i)
  float2 w3 = make_float2(-RC*(v3.x + v3.y), RC*(v3.x - v3.y));  // *conj(W8^3)=(-c,c)
  x[0]=caddf(u0,v0); x[4]=csubf(u0,v0);
  x[1]=caddf(u1,w1); x[5]=csubf(u1,w1);
  x[2]=caddf(u2,w2); x[6]=csubf(u2,w2);
  x[3]=caddf(u3,w3); x[7]=csubf(u3,w3);
}

// table twiddles: T[q*J+j] packs (w_{2q+1}, w_{2q+2}); apply post-DFT (fwd) / pre-DFT conj (inv)
__device__ __forceinline__ void tw_fwd(float2 x[8], const float4* __restrict__ T, int J, int j) {
  float4 a0 = T[j],       a1 = T[J+j];
  x[1]=cmulf(x[1],make_float2(a0.x,a0.y));
  x[2]=cmulf(x[2],make_float2(a0.z,a0.w));
  x[3]=cmulf(x[3],make_float2(a1.x,a1.y));
  x[4]=cmulf(x[4],make_float2(a1.z,a1.w));
  float4 a2 = T[2*J+j],   a3 = T[3*J+j];
  x[5]=cmulf(x[5],make_float2(a2.x,a2.y));
  x[6]=cmulf(x[6],make_float2(a2.z,a2.w));
  x[7]=cmulf(x[7],make_float2(a3.x,a3.y));
}
__device__ __forceinline__ void tw_inv(float2 x[8], const float4* __restrict__ T, int J, int j) {
  float4 a0 = T[j],       a1 = T[J+j];
  x[1]=cmulc(x[1],make_float2(a0.x,a0.y));
  x[2]=cmulc(x[2],make_float2(a0.z,a0.w));
  x[3]=cmulc(x[3],make_float2(a1.x,a1.y));
  x[4]=cmulc(x[4],make_float2(a1.z,a1.w));
  float4 a2 = T[2*J+j],   a3 = T[3*J+j];
  x[5]=cmulc(x[5],make_float2(a2.x,a2.y));
  x[6]=cmulc(x[6],make_float2(a2.z,a2.w));
  x[7]=cmulc(x[7],make_float2(a3.x,a3.y));
}

// W16^m = exp(-2*pi*i*m/16).  [r14 BUG FIX: previous table held W32^m values
// carried over from r6's CW32 -- wrong twiddle made F4 a non-Fourier map, absmax 8.7]
#define DECL_W16C \
  const float2 W16C[8] = { make_float2(1.f,0.f), \
    make_float2(0.9238795325112867f,-0.3826834323650898f), \
    make_float2(0.7071067811865476f,-0.7071067811865476f), \
    make_float2(0.3826834323650898f,-0.9238795325112867f), \
    make_float2(0.f,-1.f), \
    make_float2(-0.3826834323650898f,-0.9238795325112867f), \
    make_float2(-0.7071067811865476f,-0.7071067811865476f), \
    make_float2(-0.9238795325112867f,-0.3826834323650898f) };

// ---------------- prep: radix-8 twiddle tables, one float4 per thread ----------------
__device__ __forceinline__ float2 W8192e(long long e) {
  double ang = -2.0*M_PI*(double)(e & (MFFT-1))/(double)MFFT;
  return make_float2((float)cos(ang), (float)sin(ang));
}
__global__ void tables8_kernel(float4* __restrict__ T1, float4* __restrict__ T2,
                               float4* __restrict__ T3) {
  int idx = blockIdx.x*blockDim.x + threadIdx.x;
  if (idx < 4096) {                        // T1: stride 1024, subsize 8192: w_m = W8192^{j m}
    int q = idx >> 10, j = idx & 1023;
    float2 wa = W8192e((long long)j*(2*q+1));
    float2 wb = W8192e((long long)j*(2*q+2));
    T1[(q<<10)+j] = make_float4(wa.x, wa.y, wb.x, wb.y);
  } else if (idx < 4608) {                 // T2: stride 128, subsize 1024: W8192^{8 j m}
    int r = idx - 4096; int q = r >> 7, j = r & 127;
    float2 wa = W8192e(8LL*j*(2*q+1));
    float2 wb = W8192e(8LL*j*(2*q+2));
    T2[(q<<7)+j] = make_float4(wa.x, wa.y, wb.x, wb.y);
  } else if (idx < 4672) {                 // T3: stride 16, subsize 128: W8192^{64 j m}
    int r = idx - 4608; int q = r >> 4, j = r & 15;
    float2 wa = W8192e(64LL*j*(2*q+1));
    float2 wb = W8192e(64LL*j*(2*q+2));
    T3[(q<<4)+j] = make_float4(wa.x, wa.y, wb.x, wb.y);
  }
}

// ---------------- prep: at_roots via 4 Cauchy dots (fp64) -- validated r1..r13 ------------
__global__ void cauchy_kernel(const float* __restrict__ Lre, const float* __restrict__ Lim,
                              const float* __restrict__ Pre, const float* __restrict__ Pim,
                              const float* __restrict__ Bre, const float* __restrict__ Bim,
                              const float* __restrict__ Cri, const float* __restrict__ lstep,
                              float2* __restrict__ a_out) {
  int k = blockIdx.x*blockDim.x + threadIdx.x;
  if (k >= LSEQ) return;
  double step = exp((double)lstep[0]);
  double ang = -2.0*M_PI*(double)k/(double)LSEQ;
  double wr = cos(ang), wi = sin(ang);
  double nr = 1.0 - wr, ni = -wi;
  double dr = 1.0 + wr, di = wi;
  double dn = dr*dr + di*di;
  double gre = (2.0/step) * (nr*dr + ni*di)/dn;
  double gim = (2.0/step) * (ni*dr - nr*di)/dn;
  double cre = 2.0*dr/dn, cim = -2.0*di/dn;
  double k00r=0,k00i=0,k01r=0,k01i=0,k10r=0,k10i=0,k11r=0,k11i=0;
  for (int n = 0; n < NM; n++) {
    double lre = Lre[n], lim = Lim[n];
    double pre = Pre[n], pim = Pim[n];
    double bre = Bre[n], bim = Bim[n];
    double ccr = Cri[2*n], cci = Cri[2*n+1];
    double er = gre - lre, ei = gim - lim;
    double inv = 1.0/(er*er + ei*ei);
    double ir =  er*inv, ii = -ei*inv;
    double v00r = ccr*bre + cci*bim, v00i = ccr*bim - cci*bre;
    double v01r = ccr*pre + cci*pim, v01i = ccr*pim - cci*pre;
    double v10r = pre*bre + pim*bim, v10i = pre*bim - pim*bre;
    double v11r = pre*pre + pim*pim, v11i = 0.0;
    k00r += v00r*ir - v00i*ii;  k00i += v00r*ii + v00i*ir;
    k01r += v01r*ir - v01i*ii;  k01i += v01r*ii + v01i*ir;
    k10r += v10r*ir - v10i*ii;  k10i += v10r*ii + v10i*ir;
    k11r += v11r*ir - v11i*ii;  k11i += v11r*ii + v11i*ir;
  }
  double numr = k01r*k10r - k01i*k10i, numi = k01r*k10i + k01i*k10r;
  double der = 1.0 + k11r, dei = k11i;
  double dinv = 1.0/(der*der + dei*dei);
  double qr = (numr*der + numi*dei)*dinv;
  double qi = (numi*der - numr*dei)*dinv;
  double tr = k00r - qr, ti = k00i - qi;
  double ar = cre*tr - cim*ti, ai = cre*ti + cim*tr;
  a_out[k] = make_float2((float)ar, (float)ai);
}

// ---------------- prep: K[l] = Re(IDFT_L(a))[l], 64 lanes per output ----------------
__global__ void ktime_kernel(const float2* __restrict__ a, float* __restrict__ K) {
  int lane = threadIdx.x & 63;
  int l = blockIdx.x * (blockDim.x >> 6) + (threadIdx.x >> 6);
  if (l >= LSEQ) return;
  double ang0 = 2.0*M_PI*(double)((l*lane) & (LSEQ-1))/(double)LSEQ;
  double tr = cos(ang0), ti = sin(ang0);
  double ang1 = 2.0*M_PI*(double)(l & 63)/64.0;
  double wr = cos(ang1), wi = sin(ang1);
  double acc = 0.0;
  for (int k = 0; k < 64; k++) {
    float2 ak = a[lane + (k << 6)];
    acc += (double)ak.x*tr - (double)ak.y*ti;
    double ntr = tr*wr - ti*wi;
    ti = tr*wi + ti*wr;
    tr = ntr;
  }
  for (int off = 32; off > 0; off >>= 1) acc += __shfl_down(acc, off);
  if (lane == 0) K[l] = (float)(acc/(double)LSEQ);
}

// ---------------- prep: KdE/KdO = fwd chain(pad(K + D*delta)) / 8192, even/odd split ------
// Runs the IDENTICAL fwd chain as conv8 -> permutation self-consistency, no explicit
// digit-reversal bookkeeping.
__global__ void kd8_kernel(const float* __restrict__ K, const float* __restrict__ Dp,
                           const float4* __restrict__ T1, const float4* __restrict__ T2,
                           const float4* __restrict__ T3,
                           float2* __restrict__ KdE, float2* __restrict__ KdO) {
  __shared__ float2 z[MFFT];
  const int t = threadIdx.x;
  float2 x[8];
  // P1: stride 1024, j=t; fold D into K[0] (time domain)
  #pragma unroll
  for (int k = 0; k < 4; k++) {
    float v = K[t + (k<<10)];
    if (t == 0 && k == 0) v += Dp[0];
    x[k] = make_float2(v, 0.f);
  }
  #pragma unroll
  for (int k = 4; k < 8; k++) x[k] = make_float2(0.f, 0.f);
  dft8_fwd(x); tw_fwd(x, T1, 1024, t);
  #pragma unroll
  for (int m = 0; m < 8; m++) z[ZS(t + (m<<10))] = x[m];
  __syncthreads();
  // P2: stride 128
  {
    const int j2 = t & 127, gb2 = (t>>7)<<10;
    int ai[8];
    #pragma unroll
    for (int m = 0; m < 8; m++) ai[m] = ZS(gb2 + j2 + (m<<7));
    #pragma unroll
    for (int m = 0; m < 8; m++) x[m] = z[ai[m]];
    dft8_fwd(x); tw_fwd(x, T2, 128, j2);
    #pragma unroll
    for (int m = 0; m < 8; m++) z[ai[m]] = x[m];
  }
  __syncthreads();
  // P3: stride 16
  {
    const int j3 = t & 15, gb3 = (t>>4)<<7;
    int ai[8];
    #pragma unroll
    for (int m = 0; m < 8; m++) ai[m] = ZS(gb3 + j3 + (m<<4));
    #pragma unroll
    for (int m = 0; m < 8; m++) x[m] = z[ai[m]];
    dft8_fwd(x); tw_fwd(x, T3, 16, j3);
    #pragma unroll
    for (int m = 0; m < 8; m++) z[ai[m]] = x[m];
  }
  __builtin_amdgcn_wave_barrier();      // P3->F4 producers are same-wave (mapping verified)
  // F4: stride 2 (const W16 twiddles) + final r2 via shfl; store scaled spectrum
  {
    DECL_W16C
    const int G4 = t>>1, j1 = t & 1, gb4 = G4<<4;
    #pragma unroll
    for (int m = 0; m < 8; m++) x[m] = z[ZS(gb4 + j1 + (m<<1))];
    dft8_fwd(x);
    #pragma unroll
    for (int m = 1; m < 8; m++) {
      float2 wm = j1 ? W16C[m] : make_float2(1.f, 0.f);
      x[m] = cmulf(x[m], wm);
    }
    const float sc = 1.0f/8192.0f;
    float2* kout = (j1 ? KdO : KdE) + (G4<<3);
    #pragma unroll
    for (int p = 0; p < 8; p++) {
      float ox = __shfl_xor(x[p].x, 1);
      float oy = __shfl_xor(x[p].y, 1);
      float2 v = j1 ? make_float2(ox - x[p].x, oy - x[p].y)
                    : make_float2(x[p].x + ox, x[p].y + oy);
      kout[p] = make_float2(v.x*sc, v.y*sc);
    }
  }
}

// ---------------- main: 2 rows/block, 8192-pt FFT, 1024 thr x 8 elems, radix-8^4 ----------
// OCCUPANCY EXPERIMENT: x[8]=16 data regs targets the <=64-VGPR class -> 8 waves/SIMD
// (vs r13's 80 regs -> 4/SIMD). LDS 64KB -> 2 blocks x 16 waves = 32 waves/CU (2x r13).
// (1024,4) forces cap 64 (empirical rule cap=256/arg2). Spill tripwire: WRITE >> 65.5MB.
__global__ __launch_bounds__(1024, 4)
void conv8_kernel(const float* __restrict__ u,
                  const float4* __restrict__ T1, const float4* __restrict__ T2,
                  const float4* __restrict__ T3,
                  const float2* __restrict__ KdE, const float2* __restrict__ KdO,
                  float* __restrict__ out) {
  __shared__ float2 z[MFFT];
  const int t = threadIdx.x;
  const int r0 = blockIdx.x, r1 = blockIdx.x + (NBH/2);
  const float* u0 = u + (size_t)r0*LSEQ;
  const float* u1 = u + (size_t)r1*LSEQ;
  float2 x[8];
  // ---- P1 fwd: stride 1024, j=t ----
  {
    #pragma unroll
    for (int k = 0; k < 4; k++)
      x[k] = make_float2(u0[t + (k<<10)], u1[t + (k<<10)]);
    #pragma unroll
    for (int k = 4; k < 8; k++) x[k] = make_float2(0.f, 0.f);
    dft8_fwd(x); tw_fwd(x, T1, 1024, t);
    #pragma unroll
    for (int m = 0; m < 8; m++) z[ZS(t + (m<<10))] = x[m];
  }
  __syncthreads();
  // ---- P2 fwd: stride 128 ----
  const int j2 = t & 127, gb2 = (t>>7)<<10;
  {
    int ai[8];
    #pragma unroll
    for (int m = 0; m < 8; m++) ai[m] = ZS(gb2 + j2 + (m<<7));
    #pragma unroll
    for (int m = 0; m < 8; m++) x[m] = z[ai[m]];
    dft8_fwd(x); tw_fwd(x, T2, 128, j2);
    #pragma unroll
    for (int m = 0; m < 8; m++) z[ai[m]] = x[m];
  }
  __syncthreads();
  // ---- P3 fwd: stride 16 ----
  const int j3 = t & 15, gb3 = (t>>4)<<7;
  {
    int ai[8];
    #pragma unroll
    for (int m = 0; m < 8; m++) ai[m] = ZS(gb3 + j3 + (m<<4));
    #pragma unroll
    for (int m = 0; m < 8; m++) x[m] = z[ai[m]];
    dft8_fwd(x); tw_fwd(x, T3, 16, j3);
    #pragma unroll
    for (int m = 0; m < 8; m++) z[ai[m]] = x[m];
  }
  __builtin_amdgcn_wave_barrier();   // F4 wave reads [512w,512w+512) written by same wave
  // ---- F4: r8(s=2) + r2-shfl + xKd + r2-shfl-inv + r8i(s=2), all in registers ----
  {
    DECL_W16C
    const int G4 = t>>1, j1 = t & 1, gb4 = G4<<4;
    int ai[8];
    #pragma unroll
    for (int m = 0; m < 8; m++) ai[m] = ZS(gb4 + j1 + (m<<1));
    #pragma unroll
    for (int m = 0; m < 8; m++) x[m] = z[ai[m]];
    dft8_fwd(x);
    #pragma unroll
    for (int m = 1; m < 8; m++) {
      float2 wm = j1 ? W16C[m] : make_float2(1.f, 0.f);
      x[m] = cmulf(x[m], wm);
    }
    // final r2 (pairs = even/odd thread slots) + pointwise xKd, staged 2 kd at a time
    const float4* kp = (const float4*)((j1 ? KdO : KdE) + (G4<<3));
    #pragma unroll
    for (int p2 = 0; p2 < 4; p2++) {
      float4 kq = kp[p2];
      #pragma unroll
      for (int s = 0; s < 2; s++) {
        const int p = 2*p2 + s;
        float2 kd = s ? make_float2(kq.z, kq.w) : make_float2(kq.x, kq.y);
        float ox = __shfl_xor(x[p].x, 1);
        float oy = __shfl_xor(x[p].y, 1);
        float2 v = j1 ? make_float2(ox - x[p].x, oy - x[p].y)   // pos odd: a-b
                      : make_float2(x[p].x + ox, x[p].y + oy);  // pos even: a+b
        x[p] = cmulf(v, kd);
      }
    }
    // r2 inverse (even = s+d, odd = s-d)
    #pragma unroll
    for (int p = 0; p < 8; p++) {
      float ox = __shfl_xor(x[p].x, 1);
      float oy = __shfl_xor(x[p].y, 1);
      x[p] = j1 ? make_float2(ox - x[p].x, oy - x[p].y)
                : make_float2(x[p].x + ox, x[p].y + oy);
    }
    // un-twiddle (conj const) + inverse r8
    #pragma unroll
    for (int m = 1; m < 8; m++) {
      float2 wm = j1 ? W16C[m] : make_float2(1.f, 0.f);
      x[m] = cmulc(x[m], wm);
    }
    dft8_inv(x);
    #pragma unroll
    for (int m = 0; m < 8; m++) z[ai[m]] = x[m];
  }
  __builtin_amdgcn_wave_barrier();
  // ---- P3 inv ----
  {
    int ai[8];
    #pragma unroll
    for (int m = 0; m < 8; m++) ai[m] = ZS(gb3 + j3 + (m<<4));
    #pragma unroll
    for (int m = 0; m < 8; m++) x[m] = z[ai[m]];
    tw_inv(x, T3, 16, j3); dft8_inv(x);
    #pragma unroll
    for (int m = 0; m < 8; m++) z[ai[m]] = x[m];
  }
  __syncthreads();
  // ---- P2 inv ----
  {
    int ai[8];
    #pragma unroll
    for (int m = 0; m < 8; m++) ai[m] = ZS(gb2 + j2 + (m<<7));
    #pragma unroll
    for (int m = 0; m < 8; m++) x[m] = z[ai[m]];
    tw_inv(x, T2, 128, j2); dft8_inv(x);
    #pragma unroll
    for (int m = 0; m < 8; m++) z[ai[m]] = x[m];
  }
  __syncthreads();
  // ---- P1 inv + store (positions >= 4096 discarded) ----
  {
    #pragma unroll
    for (int m = 0; m < 8; m++) x[m] = z[ZS(t + (m<<10))];
    tw_inv(x, T1, 1024, t); dft8_inv(x);
    float* o0 = out + (size_t)r0*LSEQ;
    float* o1 = out + (size_t)r1*LSEQ;
    #pragma unroll
    for (int m = 0; m < 4; m++) {
      int idx = t + (m<<10);
      o0[idx] = x[m].x;
      o1[idx] = x[m].y;
    }
  }
}

extern "C" void kernel_launch(void* const* d_in, const int* in_sizes, int n_in,
                              void* d_out, int out_size, void* d_ws, size_t ws_size,
                              hipStream_t stream) {
  const float* u     = (const float*)d_in[0];
  const float* Lre   = (const float*)d_in[1];
  const float* Lim   = (const float*)d_in[2];
  const float* Pre   = (const float*)d_in[3];
  const float* Pim   = (const float*)d_in[4];
  const float* Bre   = (const float*)d_in[5];
  const float* Bim   = (const float*)d_in[6];
  const float* Cri   = (const float*)d_in[7];
  const float* Dp    = (const float*)d_in[8];
  const float* lstep = (const float*)d_in[9];
  float* out = (float*)d_out;

  char* ws = (char*)d_ws;
  float2* a_ws   = (float2*)(ws);            //  32768 B : at_roots
  float*  K_ws   = (float*)(ws + 32768);     //  16384 B : K time domain
  float2* KdE_ws = (float2*)(ws + 49152);    //  32768 B : spectrum at even in-place pos, /8192
  float2* KdO_ws = (float2*)(ws + 81920);    //  32768 B : odd positions
  float4* T1_ws  = (float4*)(ws + 114688);   //  65536 B : pass-1 twiddles [4][1024]
  float4* T2_ws  = (float4*)(ws + 180224);   //   8192 B : pass-2 twiddles [4][128]
  float4* T3_ws  = (float4*)(ws + 188416);   //   1024 B : pass-3 twiddles [4][16]

  hipLaunchKernelGGL(tables8_kernel, dim3(19),   dim3(256), 0, stream,
                     T1_ws, T2_ws, T3_ws);
  hipLaunchKernelGGL(cauchy_kernel,  dim3(64),   dim3(64),  0, stream,
                     Lre, Lim, Pre, Pim, Bre, Bim, Cri, lstep, a_ws);
  hipLaunchKernelGGL(ktime_kernel,   dim3(1024), dim3(256), 0, stream, a_ws, K_ws);
  hipLaunchKernelGGL(kd8_kernel,     dim3(1),    dim3(1024), 0, stream,
                     K_ws, Dp, T1_ws, T2_ws, T3_ws, KdE_ws, KdO_ws);
  hipLaunchKernelGGL(conv8_kernel,   dim3(NBH/2), dim3(1024), 0, stream,
                     u, T1_ws, T2_ws, T3_ws, KdE_ws, KdO_ws, out);
}

// Round 16
// 105.302 us; speedup vs baseline: 1.2476x; 1.1232x over previous
//
#include <hip/hip_runtime.h>
#include <math.h>

#define LSEQ 4096
#define MFFT 8192
#define NM   64
#define NBH  4096

__device__ __forceinline__ float2 cmulf(float2 a, float2 b) {
  return make_float2(a.x*b.x - a.y*b.y, a.x*b.y + a.y*b.x);
}
// a * conj(b)
__device__ __forceinline__ float2 cmulc(float2 a, float2 b) {
  return make_float2(a.x*b.x + a.y*b.y, a.y*b.x - a.x*b.y);
}
__device__ __forceinline__ float2 caddf(float2 a, float2 b){ return make_float2(a.x+b.x, a.y+b.y); }
__device__ __forceinline__ float2 csubf(float2 a, float2 b){ return make_float2(a.x-b.x, a.y-b.y); }

// storage swizzle (r6-validated): low4 ^= bits4-7, bits4-7 ^= bits8-11. Bijective; keeps
// every 256-block in place. All pass patterns (strides 1024/128/16/2) at b64 bank floor.
__device__ __forceinline__ int ZS(int i){ return i ^ ((i>>4)&15) ^ (((i>>8)&15)<<4); }

// ---- 8-point DFT, DIF r2 cascade, outputs in natural freq order x[m]=F_m ----
__device__ __forceinline__ void dft8_fwd(float2 x[8]) {
  const float RC = 0.7071067811865476f;
  float2 u0=caddf(x[0],x[4]), v0=csubf(x[0],x[4]);
  float2 u1=caddf(x[1],x[5]), d1=csubf(x[1],x[5]);
  float2 u2=caddf(x[2],x[6]), d2=csubf(x[2],x[6]);
  float2 u3=caddf(x[3],x[7]), d3=csubf(x[3],x[7]);
  float2 v1 = make_float2(RC*(d1.x + d1.y), RC*(d1.y - d1.x));   // *W8^1=(c,-c)
  float2 v2 = make_float2(d2.y, -d2.x);                          // *(-i)
  float2 v3 = make_float2(RC*(d3.y - d3.x), -RC*(d3.x + d3.y));  // *W8^3=(-c,-c)
  float2 p0=caddf(u0,u2), q0=csubf(u0,u2);
  float2 p1=caddf(u1,u3), qt=csubf(u1,u3);
  float2 q1 = make_float2(qt.y, -qt.x);                          // *(-i)
  float2 r0=caddf(v0,v2), s0=csubf(v0,v2);
  float2 r1=caddf(v1,v3), st=csubf(v1,v3);
  float2 s1 = make_float2(st.y, -st.x);                          // *(-i)
  x[0]=caddf(p0,p1); x[4]=csubf(p0,p1);
  x[2]=caddf(q0,q1); x[6]=csubf(q0,q1);
  x[1]=caddf(r0,r1); x[5]=csubf(r0,r1);
  x[3]=caddf(s0,s1); x[7]=csubf(s0,s1);
}
// exact operation-reverse (unnormalized: inv(fwd) = 8*id; total 8192 folded into Kd)
__device__ __forceinline__ void dft8_inv(float2 x[8]) {
  const float RC = 0.7071067811865476f;
  float2 p0=caddf(x[0],x[4]), p1=csubf(x[0],x[4]);
  float2 q0=caddf(x[2],x[6]), q1=csubf(x[2],x[6]);
  float2 r0=caddf(x[1],x[5]), r1=csubf(x[1],x[5]);
  float2 s0=caddf(x[3],x[7]), s1=csubf(x[3],x[7]);
  float2 q1i = make_float2(-q1.y, q1.x);                         // *(+i)
  float2 s1i = make_float2(-s1.y, s1.x);
  float2 u0=caddf(p0,q0), u2=csubf(p0,q0);
  float2 u1=caddf(p1,q1i), u3=csubf(p1,q1i);
  float2 v0=caddf(r0,s0), v2=csubf(r0,s0);
  float2 v1=caddf(r1,s1i), v3=csubf(r1,s1i);
  float2 w1 = make_float2(RC*(v1.x - v1.y), RC*(v1.x + v1.y));   // *conj(W8^1)=(c,c)
  float2 w2 = make_float2(-v2.y, v2.x);                          // *(+i)
  float2 w3 = make_float2(-RC*(v3.x + v3.y), RC*(v3.x - v3.y));  // *conj(W8^3)=(-c,c)
  x[0]=caddf(u0,v0); x[4]=csubf(u0,v0);
  x[1]=caddf(u1,w1); x[5]=csubf(u1,w1);
  x[2]=caddf(u2,w2); x[6]=csubf(u2,w2);
  x[3]=caddf(u3,w3); x[7]=csubf(u3,w3);
}

// table twiddles: T[q*J+j] packs (w_{2q+1}, w_{2q+2}); apply post-DFT (fwd) / pre-DFT conj (inv)
__device__ __forceinline__ void tw_fwd(float2 x[8], const float4* __restrict__ T, int J, int j) {
  float4 a0 = T[j],       a1 = T[J+j];
  x[1]=cmulf(x[1],make_float2(a0.x,a0.y));
  x[2]=cmulf(x[2],make_float2(a0.z,a0.w));
  x[3]=cmulf(x[3],make_float2(a1.x,a1.y));
  x[4]=cmulf(x[4],make_float2(a1.z,a1.w));
  float4 a2 = T[2*J+j],   a3 = T[3*J+j];
  x[5]=cmulf(x[5],make_float2(a2.x,a2.y));
  x[6]=cmulf(x[6],make_float2(a2.z,a2.w));
  x[7]=cmulf(x[7],make_float2(a3.x,a3.y));
}
__device__ __forceinline__ void tw_inv(float2 x[8], const float4* __restrict__ T, int J, int j) {
  float4 a0 = T[j],       a1 = T[J+j];
  x[1]=cmulc(x[1],make_float2(a0.x,a0.y));
  x[2]=cmulc(x[2],make_float2(a0.z,a0.w));
  x[3]=cmulc(x[3],make_float2(a1.x,a1.y));
  x[4]=cmulc(x[4],make_float2(a1.z,a1.w));
  float4 a2 = T[2*J+j],   a3 = T[3*J+j];
  x[5]=cmulc(x[5],make_float2(a2.x,a2.y));
  x[6]=cmulc(x[6],make_float2(a2.z,a2.w));
  x[7]=cmulc(x[7],make_float2(a3.x,a3.y));
}

// W16^m = exp(-2*pi*i*m/16)  (r15-validated)
#define DECL_W16C \
  const float2 W16C[8] = { make_float2(1.f,0.f), \
    make_float2(0.9238795325112867f,-0.3826834323650898f), \
    make_float2(0.7071067811865476f,-0.7071067811865476f), \
    make_float2(0.3826834323650898f,-0.9238795325112867f), \
    make_float2(0.f,-1.f), \
    make_float2(-0.3826834323650898f,-0.9238795325112867f), \
    make_float2(-0.7071067811865476f,-0.7071067811865476f), \
    make_float2(-0.9238795325112867f,-0.3826834323650898f) };

__device__ __forceinline__ float2 W8192e(long long e) {
  double ang = -2.0*M_PI*(double)(e & (MFFT-1))/(double)MFFT;
  return make_float2((float)cos(ang), (float)sin(ang));
}

// ---------------- prep1: MERGED cauchy (blocks 0..63) + twiddle tables (64..82) ----------
// cauchy now uses 4 LANES PER k (n-loop split 4 ways + fp64 shfl_xor reduce): the r15
// version ran 64 serial fp64 iterations (incl. one fp64 divide each) on 1 wave/block
// (~5.5us, the largest prep item). Summation-order change only (fp64, threshold 0.2).
__global__ void prep1_kernel(const float* __restrict__ Lre, const float* __restrict__ Lim,
                             const float* __restrict__ Pre, const float* __restrict__ Pim,
                             const float* __restrict__ Bre, const float* __restrict__ Bim,
                             const float* __restrict__ Cri, const float* __restrict__ lstep,
                             float2* __restrict__ a_out,
                             float4* __restrict__ T1, float4* __restrict__ T2,
                             float4* __restrict__ T3) {
  if (blockIdx.x >= 64) {
    // ---- twiddle tables, one float4 per thread (r15-validated values) ----
    int idx = (blockIdx.x - 64)*blockDim.x + threadIdx.x;
    if (idx < 4096) {                        // T1: stride 1024: w_m = W8192^{j m}
      int q = idx >> 10, j = idx & 1023;
      float2 wa = W8192e((long long)j*(2*q+1));
      float2 wb = W8192e((long long)j*(2*q+2));
      T1[(q<<10)+j] = make_float4(wa.x, wa.y, wb.x, wb.y);
    } else if (idx < 4608) {                 // T2: stride 128: W8192^{8 j m}
      int r = idx - 4096; int q = r >> 7, j = r & 127;
      float2 wa = W8192e(8LL*j*(2*q+1));
      float2 wb = W8192e(8LL*j*(2*q+2));
      T2[(q<<7)+j] = make_float4(wa.x, wa.y, wb.x, wb.y);
    } else if (idx < 4672) {                 // T3: stride 16: W8192^{64 j m}
      int r = idx - 4608; int q = r >> 4, j = r & 15;
      float2 wa = W8192e(64LL*j*(2*q+1));
      float2 wb = W8192e(64LL*j*(2*q+2));
      T3[(q<<4)+j] = make_float4(wa.x, wa.y, wb.x, wb.y);
    }
    return;
  }
  // ---- cauchy: k = 64*block + tid/4, 4 sub-lanes split the n-loop ----
  const int tid = threadIdx.x;
  const int k = (blockIdx.x << 6) + (tid >> 2);
  const int sub = tid & 3;
  double step = exp((double)lstep[0]);
  double ang = -2.0*M_PI*(double)k/(double)LSEQ;
  double wr = cos(ang), wi = sin(ang);
  double nr = 1.0 - wr, ni = -wi;
  double dr = 1.0 + wr, di = wi;
  double dn = dr*dr + di*di;
  double gre = (2.0/step) * (nr*dr + ni*di)/dn;
  double gim = (2.0/step) * (ni*dr - nr*di)/dn;
  double cre = 2.0*dr/dn, cim = -2.0*di/dn;
  double k00r=0,k00i=0,k01r=0,k01i=0,k10r=0,k10i=0,k11r=0,k11i=0;
  for (int n = sub; n < NM; n += 4) {
    double lre = Lre[n], lim = Lim[n];
    double pre = Pre[n], pim = Pim[n];
    double bre = Bre[n], bim = Bim[n];
    double ccr = Cri[2*n], cci = Cri[2*n+1];
    double er = gre - lre, ei = gim - lim;
    double inv = 1.0/(er*er + ei*ei);
    double ir =  er*inv, ii = -ei*inv;
    double v00r = ccr*bre + cci*bim, v00i = ccr*bim - cci*bre;
    double v01r = ccr*pre + cci*pim, v01i = ccr*pim - cci*pre;
    double v10r = pre*bre + pim*bim, v10i = pre*bim - pim*bre;
    double v11r = pre*pre + pim*pim, v11i = 0.0;
    k00r += v00r*ir - v00i*ii;  k00i += v00r*ii + v00i*ir;
    k01r += v01r*ir - v01i*ii;  k01i += v01r*ii + v01i*ir;
    k10r += v10r*ir - v10i*ii;  k10i += v10r*ii + v10i*ir;
    k11r += v11r*ir - v11i*ii;  k11i += v11r*ii + v11i*ir;
  }
  // reduce the 8 accumulators across the 4 sub-lanes (fp64 shfl butterfly)
  #pragma unroll
  for (int d = 1; d <= 2; d <<= 1) {
    k00r += __shfl_xor(k00r, d);  k00i += __shfl_xor(k00i, d);
    k01r += __shfl_xor(k01r, d);  k01i += __shfl_xor(k01i, d);
    k10r += __shfl_xor(k10r, d);  k10i += __shfl_xor(k10i, d);
    k11r += __shfl_xor(k11r, d);  k11i += __shfl_xor(k11i, d);
  }
  if (sub == 0) {
    double numr = k01r*k10r - k01i*k10i, numi = k01r*k10i + k01i*k10r;
    double der = 1.0 + k11r, dei = k11i;
    double dinv = 1.0/(der*der + dei*dei);
    double qr = (numr*der + numi*dei)*dinv;
    double qi = (numi*der - numr*dei)*dinv;
    double tr = k00r - qr, ti = k00i - qi;
    double ar = cre*tr - cim*ti, ai = cre*ti + cim*tr;
    a_out[k] = make_float2((float)ar, (float)ai);
  }
}

// ---------------- prep: K[l] = Re(IDFT_L(a))[l], 64 lanes per output ----------------
__global__ void ktime_kernel(const float2* __restrict__ a, float* __restrict__ K) {
  int lane = threadIdx.x & 63;
  int l = blockIdx.x * (blockDim.x >> 6) + (threadIdx.x >> 6);
  if (l >= LSEQ) return;
  double ang0 = 2.0*M_PI*(double)((l*lane) & (LSEQ-1))/(double)LSEQ;
  double tr = cos(ang0), ti = sin(ang0);
  double ang1 = 2.0*M_PI*(double)(l & 63)/64.0;
  double wr = cos(ang1), wi = sin(ang1);
  double acc = 0.0;
  for (int k = 0; k < 64; k++) {
    float2 ak = a[lane + (k << 6)];
    acc += (double)ak.x*tr - (double)ak.y*ti;
    double ntr = tr*wr - ti*wi;
    ti = tr*wi + ti*wr;
    tr = ntr;
  }
  for (int off = 32; off > 0; off >>= 1) acc += __shfl_down(acc, off);
  if (lane == 0) K[l] = (float)(acc/(double)LSEQ);
}

// ---------------- prep: KdE/KdO = fwd chain(pad(K + D*delta)) / 8192, even/odd split ------
// Runs the IDENTICAL fwd chain as conv8 -> permutation self-consistency.
__global__ void kd8_kernel(const float* __restrict__ K, const float* __restrict__ Dp,
                           const float4* __restrict__ T1, const float4* __restrict__ T2,
                           const float4* __restrict__ T3,
                           float2* __restrict__ KdE, float2* __restrict__ KdO) {
  __shared__ float2 z[MFFT];
  const int t = threadIdx.x;
  float2 x[8];
  // P1: stride 1024, j=t; fold D into K[0] (time domain)
  #pragma unroll
  for (int k = 0; k < 4; k++) {
    float v = K[t + (k<<10)];
    if (t == 0 && k == 0) v += Dp[0];
    x[k] = make_float2(v, 0.f);
  }
  #pragma unroll
  for (int k = 4; k < 8; k++) x[k] = make_float2(0.f, 0.f);
  dft8_fwd(x); tw_fwd(x, T1, 1024, t);
  #pragma unroll
  for (int m = 0; m < 8; m++) z[ZS(t + (m<<10))] = x[m];
  __syncthreads();
  // P2: stride 128
  {
    const int j2 = t & 127, gb2 = (t>>7)<<10;
    int ai[8];
    #pragma unroll
    for (int m = 0; m < 8; m++) ai[m] = ZS(gb2 + j2 + (m<<7));
    #pragma unroll
    for (int m = 0; m < 8; m++) x[m] = z[ai[m]];
    dft8_fwd(x); tw_fwd(x, T2, 128, j2);
    #pragma unroll
    for (int m = 0; m < 8; m++) z[ai[m]] = x[m];
  }
  __syncthreads();
  // P3: stride 16
  {
    const int j3 = t & 15, gb3 = (t>>4)<<7;
    int ai[8];
    #pragma unroll
    for (int m = 0; m < 8; m++) ai[m] = ZS(gb3 + j3 + (m<<4));
    #pragma unroll
    for (int m = 0; m < 8; m++) x[m] = z[ai[m]];
    dft8_fwd(x); tw_fwd(x, T3, 16, j3);
    #pragma unroll
    for (int m = 0; m < 8; m++) z[ai[m]] = x[m];
  }
  __builtin_amdgcn_wave_barrier();      // P3->F4 producers are same-wave (mapping verified)
  // F4: stride 2 (const W16 twiddles) + final r2 via shfl; store scaled spectrum
  {
    DECL_W16C
    const int G4 = t>>1, j1 = t & 1, gb4 = G4<<4;
    #pragma unroll
    for (int m = 0; m < 8; m++) x[m] = z[ZS(gb4 + j1 + (m<<1))];
    dft8_fwd(x);
    #pragma unroll
    for (int m = 1; m < 8; m++) {
      float2 wm = j1 ? W16C[m] : make_float2(1.f, 0.f);
      x[m] = cmulf(x[m], wm);
    }
    const float sc = 1.0f/8192.0f;
    float2* kout = (j1 ? KdO : KdE) + (G4<<3);
    #pragma unroll
    for (int p = 0; p < 8; p++) {
      float ox = __shfl_xor(x[p].x, 1);
      float oy = __shfl_xor(x[p].y, 1);
      float2 v = j1 ? make_float2(ox - x[p].x, oy - x[p].y)
                    : make_float2(x[p].x + ox, x[p].y + oy);
      kout[p] = make_float2(v.x*sc, v.y*sc);
    }
  }
}

// ---------------- main: 2 rows/block, 8192-pt FFT, 1024 thr x 8 elems, radix-8^4 ----------
// r15-VALIDATED BEST: VGPR 60 (<=64 class -> 8 waves/SIMD), 2 blocks x 16 waves = 32
// waves/CU, zero spill, conv ~102us. BYTE-IDENTICAL to r15 -- do not touch.
__global__ __launch_bounds__(1024, 4)
void conv8_kernel(const float* __restrict__ u,
                  const float4* __restrict__ T1, const float4* __restrict__ T2,
                  const float4* __restrict__ T3,
                  const float2* __restrict__ KdE, const float2* __restrict__ KdO,
                  float* __restrict__ out) {
  __shared__ float2 z[MFFT];
  const int t = threadIdx.x;
  const int r0 = blockIdx.x, r1 = blockIdx.x + (NBH/2);
  const float* u0 = u + (size_t)r0*LSEQ;
  const float* u1 = u + (size_t)r1*LSEQ;
  float2 x[8];
  // ---- P1 fwd: stride 1024, j=t ----
  {
    #pragma unroll
    for (int k = 0; k < 4; k++)
      x[k] = make_float2(u0[t + (k<<10)], u1[t + (k<<10)]);
    #pragma unroll
    for (int k = 4; k < 8; k++) x[k] = make_float2(0.f, 0.f);
    dft8_fwd(x); tw_fwd(x, T1, 1024, t);
    #pragma unroll
    for (int m = 0; m < 8; m++) z[ZS(t + (m<<10))] = x[m];
  }
  __syncthreads();
  // ---- P2 fwd: stride 128 ----
  const int j2 = t & 127, gb2 = (t>>7)<<10;
  {
    int ai[8];
    #pragma unroll
    for (int m = 0; m < 8; m++) ai[m] = ZS(gb2 + j2 + (m<<7));
    #pragma unroll
    for (int m = 0; m < 8; m++) x[m] = z[ai[m]];
    dft8_fwd(x); tw_fwd(x, T2, 128, j2);
    #pragma unroll
    for (int m = 0; m < 8; m++) z[ai[m]] = x[m];
  }
  __syncthreads();
  // ---- P3 fwd: stride 16 ----
  const int j3 = t & 15, gb3 = (t>>4)<<7;
  {
    int ai[8];
    #pragma unroll
    for (int m = 0; m < 8; m++) ai[m] = ZS(gb3 + j3 + (m<<4));
    #pragma unroll
    for (int m = 0; m < 8; m++) x[m] = z[ai[m]];
    dft8_fwd(x); tw_fwd(x, T3, 16, j3);
    #pragma unroll
    for (int m = 0; m < 8; m++) z[ai[m]] = x[m];
  }
  __builtin_amdgcn_wave_barrier();   // F4 wave reads [512w,512w+512) written by same wave
  // ---- F4: r8(s=2) + r2-shfl + xKd + r2-shfl-inv + r8i(s=2), all in registers ----
  {
    DECL_W16C
    const int G4 = t>>1, j1 = t & 1, gb4 = G4<<4;
    int ai[8];
    #pragma unroll
    for (int m = 0; m < 8; m++) ai[m] = ZS(gb4 + j1 + (m<<1));
    #pragma unroll
    for (int m = 0; m < 8; m++) x[m] = z[ai[m]];
    dft8_fwd(x);
    #pragma unroll
    for (int m = 1; m < 8; m++) {
      float2 wm = j1 ? W16C[m] : make_float2(1.f, 0.f);
      x[m] = cmulf(x[m], wm);
    }
    // final r2 (pairs = even/odd thread slots) + pointwise xKd, staged 2 kd at a time
    const float4* kp = (const float4*)((j1 ? KdO : KdE) + (G4<<3));
    #pragma unroll
    for (int p2 = 0; p2 < 4; p2++) {
      float4 kq = kp[p2];
      #pragma unroll
      for (int s = 0; s < 2; s++) {
        const int p = 2*p2 + s;
        float2 kd = s ? make_float2(kq.z, kq.w) : make_float2(kq.x, kq.y);
        float ox = __shfl_xor(x[p].x, 1);
        float oy = __shfl_xor(x[p].y, 1);
        float2 v = j1 ? make_float2(ox - x[p].x, oy - x[p].y)   // pos odd: a-b
                      : make_float2(x[p].x + ox, x[p].y + oy);  // pos even: a+b
        x[p] = cmulf(v, kd);
      }
    }
    // r2 inverse (even = s+d, odd = s-d)
    #pragma unroll
    for (int p = 0; p < 8; p++) {
      float ox = __shfl_xor(x[p].x, 1);
      float oy = __shfl_xor(x[p].y, 1);
      x[p] = j1 ? make_float2(ox - x[p].x, oy - x[p].y)
                : make_float2(x[p].x + ox, x[p].y + oy);
    }
    // un-twiddle (conj const) + inverse r8
    #pragma unroll
    for (int m = 1; m < 8; m++) {
      float2 wm = j1 ? W16C[m] : make_float2(1.f, 0.f);
      x[m] = cmulc(x[m], wm);
    }
    dft8_inv(x);
    #pragma unroll
    for (int m = 0; m < 8; m++) z[ai[m]] = x[m];
  }
  __builtin_amdgcn_wave_barrier();
  // ---- P3 inv ----
  {
    int ai[8];
    #pragma unroll
    for (int m = 0; m < 8; m++) ai[m] = ZS(gb3 + j3 + (m<<4));
    #pragma unroll
    for (int m = 0; m < 8; m++) x[m] = z[ai[m]];
    tw_inv(x, T3, 16, j3); dft8_inv(x);
    #pragma unroll
    for (int m = 0; m < 8; m++) z[ai[m]] = x[m];
  }
  __syncthreads();
  // ---- P2 inv ----
  {
    int ai[8];
    #pragma unroll
    for (int m = 0; m < 8; m++) ai[m] = ZS(gb2 + j2 + (m<<7));
    #pragma unroll
    for (int m = 0; m < 8; m++) x[m] = z[ai[m]];
    tw_inv(x, T2, 128, j2); dft8_inv(x);
    #pragma unroll
    for (int m = 0; m < 8; m++) z[ai[m]] = x[m];
  }
  __syncthreads();
  // ---- P1 inv + store (positions >= 4096 discarded) ----
  {
    #pragma unroll
    for (int m = 0; m < 8; m++) x[m] = z[ZS(t + (m<<10))];
    tw_inv(x, T1, 1024, t); dft8_inv(x);
    float* o0 = out + (size_t)r0*LSEQ;
    float* o1 = out + (size_t)r1*LSEQ;
    #pragma unroll
    for (int m = 0; m < 4; m++) {
      int idx = t + (m<<10);
      o0[idx] = x[m].x;
      o1[idx] = x[m].y;
    }
  }
}

extern "C" void kernel_launch(void* const* d_in, const int* in_sizes, int n_in,
                              void* d_out, int out_size, void* d_ws, size_t ws_size,
                              hipStream_t stream) {
  const float* u     = (const float*)d_in[0];
  const float* Lre   = (const float*)d_in[1];
  const float* Lim   = (const float*)d_in[2];
  const float* Pre   = (const float*)d_in[3];
  const float* Pim   = (const float*)d_in[4];
  const float* Bre   = (const float*)d_in[5];
  const float* Bim   = (const float*)d_in[6];
  const float* Cri   = (const float*)d_in[7];
  const float* Dp    = (const float*)d_in[8];
  const float* lstep = (const float*)d_in[9];
  float* out = (float*)d_out;

  char* ws = (char*)d_ws;
  float2* a_ws   = (float2*)(ws);            //  32768 B : at_roots
  float*  K_ws   = (float*)(ws + 32768);     //  16384 B : K time domain
  float2* KdE_ws = (float2*)(ws + 49152);    //  32768 B : spectrum at even in-place pos, /8192
  float2* KdO_ws = (float2*)(ws + 81920);    //  32768 B : odd positions
  float4* T1_ws  = (float4*)(ws + 114688);   //  65536 B : pass-1 twiddles [4][1024]
  float4* T2_ws  = (float4*)(ws + 180224);   //   8192 B : pass-2 twiddles [4][128]
  float4* T3_ws  = (float4*)(ws + 188416);   //   1024 B : pass-3 twiddles [4][16]

  hipLaunchKernelGGL(prep1_kernel,  dim3(83),   dim3(256), 0, stream,
                     Lre, Lim, Pre, Pim, Bre, Bim, Cri, lstep, a_ws,
                     T1_ws, T2_ws, T3_ws);
  hipLaunchKernelGGL(ktime_kernel,  dim3(1024), dim3(256), 0, stream, a_ws, K_ws);
  hipLaunchKernelGGL(kd8_kernel,    dim3(1),    dim3(1024), 0, stream,
                     K_ws, Dp, T1_ws, T2_ws, T3_ws, KdE_ws, KdO_ws);
  hipLaunchKernelGGL(conv8_kernel,  dim3(NBH/2), dim3(1024), 0, stream,
                     u, T1_ws, T2_ws, T3_ws, KdE_ws, KdO_ws, out);
}